// Round 9
// baseline (403.451 us; speedup 1.0000x reference)
//
#include <hip/hip_runtime.h>
#include <math.h>

#define B_DIM  32
#define C_DIM  512
#define N_DIM  1024
#define LOG2E  1.44269504088896340736f
#define NEG_BIG (-1.0e30f)

typedef __attribute__((ext_vector_type(8))) __bf16 bf16x8;
typedef __attribute__((ext_vector_type(8))) short short8v;
typedef __attribute__((ext_vector_type(4))) short short4v;
typedef __attribute__((ext_vector_type(4))) float floatx4;

__device__ __forceinline__ unsigned short f2bf(float f) {      // RNE fp32->bf16
    unsigned u = __float_as_uint(f);
    return (unsigned short)((u + 0x7FFFu + ((u >> 16) & 1u)) >> 16);
}
__device__ __forceinline__ float bf2f(unsigned short h) {
    return __uint_as_float(((unsigned)h) << 16);
}
__device__ __forceinline__ floatx4 mfma16(short8v a, short8v b, floatx4 c) {
    return __builtin_amdgcn_mfma_f32_16x16x32_bf16(
        __builtin_bit_cast(bf16x8, a), __builtin_bit_cast(bf16x8, b), c, 0, 0, 0);
}
// non-finite -> 0 (diagnostic guard: output always finite, absmax stays readable)
__device__ __forceinline__ float fin(float v) {
    return (__builtin_fabsf(v) <= 1.0e30f) ? v : 0.0f;
}

// Raw barrier that does NOT drain vmcnt (unlike __syncthreads). Writer-side
// lgkmcnt(0) drains this wave's LDS writes; "memory" clobbers pin ordering.
#define BAR_LDS()  do {                                            \
    asm volatile("s_waitcnt lgkmcnt(0)" ::: "memory");             \
    __builtin_amdgcn_s_barrier();                                  \
    asm volatile("" ::: "memory");                                 \
} while (0)

// ---------------------------------------------------------------------------
// Weight prep (once per launch): Wq,Wk -> hi/lo bf16 [128][512]; Wv -> bf16.
// Written into the head of d_out (scratch until attn overwrites all of it).
// 640 blocks, one row each; threads 0..127 convert one float4 each.
// ---------------------------------------------------------------------------
__global__ __launch_bounds__(256) void wprep_kernel(
    const float* __restrict__ Wq, const float* __restrict__ Wk,
    const float* __restrict__ Wv,
    unsigned short* __restrict__ Wqkh, unsigned short* __restrict__ Wqkl,
    unsigned short* __restrict__ Wvb)
{
    const int r = blockIdx.x;            // 0..639
    const int t = threadIdx.x;
    if (t >= 128) return;
    if (r < 128) {
        const float* src = (r < 64) ? (Wq + (size_t)r * C_DIM)
                                    : (Wk + (size_t)(r - 64) * C_DIM);
        const float4 v = ((const float4*)src)[t];
        const float fv[4] = {v.x, v.y, v.z, v.w};
        short4v sh, sl;
        #pragma unroll
        for (int j = 0; j < 4; ++j) {
            const unsigned short h = f2bf(fv[j]);
            sh[j] = (short)h;
            sl[j] = (short)f2bf(fv[j] - bf2f(h));
        }
        *(short4v*)(Wqkh + (size_t)r * C_DIM + t*4) = sh;
        *(short4v*)(Wqkl + (size_t)r * C_DIM + t*4) = sl;
    } else {
        const int rv = r - 128;
        const float4 v = ((const float4*)(Wv + (size_t)rv * C_DIM))[t];
        short4v s;
        s[0] = (short)f2bf(v.x); s[1] = (short)f2bf(v.y);
        s[2] = (short)f2bf(v.z); s[3] = (short)f2bf(v.w);
        *(short4v*)(Wvb + (size_t)rv * C_DIM + t*4) = s;
    }
}

// ---------------------------------------------------------------------------
// Transpose+split x: [b][512][1024] fp32 -> xth/xtl bf16 [b][1024][512]
// ---------------------------------------------------------------------------
__global__ __launch_bounds__(256) void tx2_kernel(
    const float* __restrict__ x,
    unsigned short* __restrict__ xth, unsigned short* __restrict__ xtl)
{
    __shared__ float tile[64][65];
    const int n0 = blockIdx.x * 64, c0 = blockIdx.y * 64, b = blockIdx.z;
    const int t = threadIdx.x;

    #pragma unroll
    for (int p = 0; p < 4; ++p) {
        const int r = (t >> 4) + 16 * p;
        const float4 v = *(const float4*)(x + ((size_t)b*C_DIM + c0 + r)*N_DIM
                                          + n0 + (t & 15)*4);
        tile[r][(t&15)*4+0] = v.x;  tile[r][(t&15)*4+1] = v.y;
        tile[r][(t&15)*4+2] = v.z;  tile[r][(t&15)*4+3] = v.w;
    }
    __syncthreads();
    #pragma unroll
    for (int p = 0; p < 2; ++p) {
        const int rn = (t >> 3) + 32 * p;
        const int c8 = (t & 7) * 8;
        short8v hi, lo;
        #pragma unroll
        for (int j = 0; j < 8; ++j) {
            const float f = tile[c8 + j][rn];
            const unsigned short h = f2bf(f);
            hi[j] = (short)h;
            lo[j] = (short)f2bf(f - bf2f(h));
        }
        const size_t base = ((size_t)b*N_DIM + n0 + rn)*C_DIM + c0 + c8;
        *(short8v*)(xth + base) = hi;
        *(short8v*)(xtl + base) = lo;
    }
}

// ---------------------------------------------------------------------------
// Q,K projection, split-bf16 MFMA (R6-proven math); B-stage now copies
// pre-converted weights (wprep) instead of converting per block.
// ---------------------------------------------------------------------------
__global__ __launch_bounds__(256) void qkproj_mfma(
    const unsigned short* __restrict__ xth, const unsigned short* __restrict__ xtl,
    const unsigned short* __restrict__ Wqkh, const unsigned short* __restrict__ Wqkl,
    const float* __restrict__ bq, const float* __restrict__ bk,
    unsigned short* __restrict__ qkt)
{
    __shared__ unsigned short Ah[128][40], Al[128][40];
    __shared__ unsigned short Bh[128][40], Bl[128][40];
    const int b = blockIdx.z, n0 = blockIdx.x * 128;
    const int t = threadIdx.x, w = t >> 6, l = t & 63;
    const int la = l & 15, lb = l >> 4;
    const int nh = (w & 1) * 64, oh = (w >> 1) * 64;

    floatx4 acc[4][4];
    #pragma unroll
    for (int i = 0; i < 4; ++i)
        #pragma unroll
        for (int j = 0; j < 4; ++j) acc[i][j] = (floatx4)0.0f;

    for (int k0 = 0; k0 < C_DIM; k0 += 32) {
        #pragma unroll
        for (int p = 0; p < 2; ++p) {       // A + B stages: 2x256x8 = 128x32 each
            const int idx = t + 256*p, row = idx >> 2, ch = idx & 3;
            const size_t g = ((size_t)b*N_DIM + n0 + row)*C_DIM + k0 + ch*8;
            *(short8v*)&Ah[row][ch*8] = *(const short8v*)(xth + g);
            *(short8v*)&Al[row][ch*8] = *(const short8v*)(xtl + g);
            const size_t gw = (size_t)row*C_DIM + k0 + ch*8;
            *(short8v*)&Bh[row][ch*8] = *(const short8v*)(Wqkh + gw);
            *(short8v*)&Bl[row][ch*8] = *(const short8v*)(Wqkl + gw);
        }
        __syncthreads();

        short8v ahf[4], alf[4], bhf[4], blf[4];
        #pragma unroll
        for (int nt = 0; nt < 4; ++nt) {
            ahf[nt] = *(const short8v*)&Ah[nh + nt*16 + la][lb*8];
            alf[nt] = *(const short8v*)&Al[nh + nt*16 + la][lb*8];
        }
        #pragma unroll
        for (int ot = 0; ot < 4; ++ot) {
            bhf[ot] = *(const short8v*)&Bh[oh + ot*16 + la][lb*8];
            blf[ot] = *(const short8v*)&Bl[oh + ot*16 + la][lb*8];
        }
        #pragma unroll
        for (int nt = 0; nt < 4; ++nt)
            #pragma unroll
            for (int ot = 0; ot < 4; ++ot) {
                acc[nt][ot] = mfma16(ahf[nt], bhf[ot], acc[nt][ot]);
                acc[nt][ot] = mfma16(ahf[nt], blf[ot], acc[nt][ot]);
                acc[nt][ot] = mfma16(alf[nt], bhf[ot], acc[nt][ot]);
            }
        __syncthreads();
    }

    const int plane = (oh == 0) ? 0 : 2;     // wave-uniform
    #pragma unroll
    for (int ot = 0; ot < 4; ++ot) {
        const int o = oh + ot*16 + la;
        const int c = o & 63;
        const float bias = (oh == 0) ? bq[o] : bk[o - 64];
        #pragma unroll
        for (int nt = 0; nt < 4; ++nt)
            #pragma unroll
            for (int r = 0; r < 4; ++r) {
                const int n = n0 + nh + nt*16 + lb*4 + r;
                const float f = acc[nt][ot][r] + bias;
                const unsigned short h = f2bf(f);
                const unsigned short lo16 = f2bf(f - bf2f(h));
                qkt[(((size_t)b*4 + plane    )*N_DIM + n)*64 + c] = h;
                qkt[(((size_t)b*4 + plane + 1)*N_DIM + n)*64 + c] = lo16;
            }
    }
}

// ---------------------------------------------------------------------------
// V projection, bf16 MFMA (R6-proven math); B-stage copies pre-converted Wv.
// ---------------------------------------------------------------------------
__global__ __launch_bounds__(256) void vproj_mfma(
    const unsigned short* __restrict__ xt,
    const unsigned short* __restrict__ Wvb, const float* __restrict__ bvv,
    unsigned short* __restrict__ vbf)
{
    __shared__ unsigned short Axs[128][40];
    __shared__ unsigned short Bws[128][40];
    const int b = blockIdx.z, m0 = blockIdx.x * 128, c0 = blockIdx.y * 128;
    const int t = threadIdx.x, w = t >> 6, l = t & 63;
    const int la = l & 15, lb = l >> 4;
    const int mh = (w & 1) * 64, chh = (w >> 1) * 64;

    floatx4 acc[4][4];
    #pragma unroll
    for (int i = 0; i < 4; ++i)
        #pragma unroll
        for (int j = 0; j < 4; ++j) acc[i][j] = (floatx4)0.0f;

    for (int k0 = 0; k0 < C_DIM; k0 += 32) {
        #pragma unroll
        for (int p = 0; p < 2; ++p) {        // A + B: 2x256x8 = 128x32 each
            const int idx = t + 256 * p;
            const int row = idx >> 2, ch = idx & 3;
            *(short8v*)&Axs[row][ch*8] =
                *(const short8v*)(xt + ((size_t)b*N_DIM + m0 + row)*C_DIM + k0 + ch*8);
            *(short8v*)&Bws[row][ch*8] =
                *(const short8v*)(Wvb + (size_t)(c0 + row)*C_DIM + k0 + ch*8);
        }
        __syncthreads();
        short8v af[4], bfv[4];
        #pragma unroll
        for (int mt = 0; mt < 4; ++mt)
            af[mt] = *(const short8v*)&Axs[mh + mt*16 + la][lb*8];
        #pragma unroll
        for (int ct = 0; ct < 4; ++ct)
            bfv[ct] = *(const short8v*)&Bws[chh + ct*16 + la][lb*8];
        #pragma unroll
        for (int mt = 0; mt < 4; ++mt)
            #pragma unroll
            for (int ct = 0; ct < 4; ++ct)
                acc[mt][ct] = mfma16(af[mt], bfv[ct], acc[mt][ct]);
        __syncthreads();
    }
    #pragma unroll
    for (int ct = 0; ct < 4; ++ct) {
        const int c = c0 + chh + ct*16 + la;
        const float bias = bvv[c];
        #pragma unroll
        for (int mt = 0; mt < 4; ++mt) {
            const int m = m0 + mh + mt*16 + lb*4;
            short4v s;
            #pragma unroll
            for (int r = 0; r < 4; ++r) s[r] = (short)f2bf(acc[mt][ct][r] + bias);
            *(short4v*)(vbf + ((size_t)b*C_DIM + c)*N_DIM + m) = s;
        }
    }
}

// ---------------------------------------------------------------------------
// Fused attention, QBLK=64 (512 blocks = 2/CU, all resident), 2 barriers/iter:
//  P0: prefetch V frags (this iter) + K tile (next iter) into registers
//  P1: energy MFMA -> S                         | B1
//  P1.5+P2: K regs -> LDS  ||  softmax S -> Pb  | B2
//  P3: rescale + PV (V from regs)               | (no barrier: audited)
// Hazards: Kwr(i)->Krd(i+1) sep by B2(i); Krd(i+1)->Kwr(i+1) by B1(i+1);
// Swr(i+1)->Srd(i) by B2(i); Pbrd(i)->Pbwr(i+1) by B1(i+1).
// ---------------------------------------------------------------------------
__global__ __launch_bounds__(256, 2) void attn_mfma(
    const unsigned short* __restrict__ qkt,  // [b][4][1024][64]
    const unsigned short* __restrict__ vbf,  // [b][512][1024]
    const float* __restrict__ x,
    const float* __restrict__ alpha_p,
    float* __restrict__ out)
{
    __shared__ unsigned short Qh[64][72], Ql[64][72];
    __shared__ unsigned short Kh[64][72], Kl[64][72];
    __shared__ __align__(16) float S[64][68];
    __shared__ unsigned short Pb[64][72];
    __shared__ float row_m[64], row_l[64], row_scale[64];

    const int id  = blockIdx.x;
    const int lin = (id & 7) * 64 + (id >> 3);   // XCD-contiguous (512%8==0)
    const int b   = lin >> 4;
    const int n0  = (lin & 15) * 64;

    const int t = threadIdx.x, w = t >> 6, l = t & 63;
    const int la = l & 15, lb = l >> 4;
    const unsigned short* qkb = qkt + (size_t)b * 4 * N_DIM * 64;

    // ---- Q tile [64][64] both planes. Coverage: 2 passes x 256 x 8 = 64x64.
    #pragma unroll
    for (int plane = 0; plane < 2; ++plane)
        #pragma unroll
        for (int p = 0; p < 2; ++p) {
            const int idx = t + 256*p, row = idx >> 3, ch = idx & 7;
            const short8v g = *(const short8v*)(qkb + ((size_t)plane*N_DIM + n0 + row)*64 + ch*8);
            if (plane == 0) *(short8v*)&Qh[row][ch*8] = g;
            else            *(short8v*)&Ql[row][ch*8] = g;
        }
    // ---- prologue K stage (tile 0). Same coverage.
    #pragma unroll
    for (int plane = 0; plane < 2; ++plane)
        #pragma unroll
        for (int p = 0; p < 2; ++p) {
            const int idx = t + 256*p, row = idx >> 3, ch = idx & 7;
            const short8v g = *(const short8v*)(qkb + ((size_t)(2 + plane)*N_DIM + row)*64 + ch*8);
            if (plane == 0) *(short8v*)&Kh[row][ch*8] = g;
            else            *(short8v*)&Kl[row][ch*8] = g;
        }
    if (t < 64) { row_m[t] = NEG_BIG; row_l[t] = 0.0f; row_scale[t] = 1.0f; }
    __syncthreads();   // prologue: full drain once

    floatx4 acc[4][8];   // [ntile][ctile]; n = nt*16+lb*4+r, c = w*128+ct*16+la
    #pragma unroll
    for (int i = 0; i < 4; ++i)
        #pragma unroll
        for (int j = 0; j < 8; ++j) acc[i][j] = (floatx4)0.0f;

    #pragma unroll 1
    for (int it = 0; it < 16; ++it) {
        const int m0  = it * 64;
        const int m0n = (it < 15) ? (m0 + 64) : 0;   // next tile (wrap unused)

        // ---- P0: issue prefetch loads (no waits here)
        short8v vreg[2][8];
        #pragma unroll
        for (int ks = 0; ks < 2; ++ks) {
            const unsigned short* vp =
                vbf + ((size_t)b*C_DIM + w*128 + la)*N_DIM + m0 + ks*32 + lb*8;
            #pragma unroll
            for (int ct = 0; ct < 8; ++ct)
                vreg[ks][ct] = *(const short8v*)(vp + (size_t)ct*16*N_DIM);
        }
        short8v kreg[2][2];
        #pragma unroll
        for (int plane = 0; plane < 2; ++plane)
            #pragma unroll
            for (int p = 0; p < 2; ++p) {
                const int idx = t + 256*p, row = idx >> 3, ch = idx & 7;
                kreg[plane][p] = *(const short8v*)(qkb + ((size_t)(2 + plane)*N_DIM + m0n + row)*64 + ch*8);
            }

        // ---- P1: energy MFMA (split-bf16, 3 terms); wave w owns m-subtile w
        {
            floatx4 e[4] = {(floatx4)0.0f,(floatx4)0.0f,(floatx4)0.0f,(floatx4)0.0f};
            #pragma unroll
            for (int ks = 0; ks < 2; ++ks) {
                const short8v ah = *(const short8v*)&Kh[w*16 + la][ks*32 + lb*8];
                const short8v al = *(const short8v*)&Kl[w*16 + la][ks*32 + lb*8];
                #pragma unroll
                for (int nt = 0; nt < 4; ++nt) {
                    const short8v bh = *(const short8v*)&Qh[nt*16 + la][ks*32 + lb*8];
                    const short8v bl = *(const short8v*)&Ql[nt*16 + la][ks*32 + lb*8];
                    e[nt] = mfma16(ah, bh, e[nt]);
                    e[nt] = mfma16(ah, bl, e[nt]);
                    e[nt] = mfma16(al, bh, e[nt]);
                }
            }
            #pragma unroll
            for (int nt = 0; nt < 4; ++nt) {   // D[m][n] -> S[n][m]
                floatx4 ev = e[nt];
                #pragma unroll
                for (int r = 0; r < 4; ++r) ev[r] = fin(ev[r]);
                *(floatx4*)&S[nt*16 + la][w*16 + lb*4] = ev;
            }
        }
        BAR_LDS();   // B1

        // ---- P1.5: write prefetched K tile -> LDS (for next iter)
        #pragma unroll
        for (int plane = 0; plane < 2; ++plane)
            #pragma unroll
            for (int p = 0; p < 2; ++p) {
                const int idx = t + 256*p, row = idx >> 3, ch = idx & 7;
                if (plane == 0) *(short8v*)&Kh[row][ch*8] = kreg[plane][p];
                else            *(short8v*)&Kl[row][ch*8] = kreg[plane][p];
            }
        // ---- P2: online softmax, 2 rows/thread, emit P as bf16
        #pragma unroll
        for (int sp = 0; sp < 2; ++sp) {
            const int row = (t >> 3) + 32*sp, seg = t & 7;
            const float4 sa = *(const float4*)&S[row][seg*8];
            const float4 sb = *(const float4*)&S[row][seg*8 + 4];
            float mx = fmaxf(fmaxf(fmaxf(sa.x,sa.y), fmaxf(sa.z,sa.w)),
                             fmaxf(fmaxf(sb.x,sb.y), fmaxf(sb.z,sb.w)));
            mx = fmaxf(mx, __shfl_xor(mx, 1));
            mx = fmaxf(mx, __shfl_xor(mx, 2));
            mx = fmaxf(mx, __shfl_xor(mx, 4));
            const float m_old = row_m[row];
            const float m_new = fmaxf(m_old, mx);
            const float p0 = exp2f((sa.x - m_new) * LOG2E);
            const float p1 = exp2f((sa.y - m_new) * LOG2E);
            const float p2 = exp2f((sa.z - m_new) * LOG2E);
            const float p3 = exp2f((sa.w - m_new) * LOG2E);
            const float p4 = exp2f((sb.x - m_new) * LOG2E);
            const float p5 = exp2f((sb.y - m_new) * LOG2E);
            const float p6 = exp2f((sb.z - m_new) * LOG2E);
            const float p7 = exp2f((sb.w - m_new) * LOG2E);
            float sum = ((p0+p1)+(p2+p3)) + ((p4+p5)+(p6+p7));
            sum += __shfl_xor(sum, 1);
            sum += __shfl_xor(sum, 2);
            sum += __shfl_xor(sum, 4);
            short8v pk;
            pk[0]=(short)f2bf(p0); pk[1]=(short)f2bf(p1);
            pk[2]=(short)f2bf(p2); pk[3]=(short)f2bf(p3);
            pk[4]=(short)f2bf(p4); pk[5]=(short)f2bf(p5);
            pk[6]=(short)f2bf(p6); pk[7]=(short)f2bf(p7);
            *(short8v*)&Pb[row][seg*8] = pk;
            if (seg == 0) {
                const float sc = exp2f((m_old - m_new) * LOG2E);
                row_scale[row] = sc;
                row_l[row] = row_l[row] * sc + sum;
                row_m[row] = m_new;
            }
        }
        BAR_LDS();   // B2

        // ---- P3: rescale + PV MFMA (V from prefetch regs); no barrier after
        {
            float fsc[4][4];
            #pragma unroll
            for (int nt = 0; nt < 4; ++nt)
                #pragma unroll
                for (int r = 0; r < 4; ++r) fsc[nt][r] = row_scale[nt*16 + lb*4 + r];
            #pragma unroll
            for (int nt = 0; nt < 4; ++nt)
                #pragma unroll
                for (int ct = 0; ct < 8; ++ct)
                    #pragma unroll
                    for (int r = 0; r < 4; ++r) acc[nt][ct][r] *= fsc[nt][r];
        }
        #pragma unroll
        for (int ks = 0; ks < 2; ++ks) {
            short8v pa[4];
            #pragma unroll
            for (int nt = 0; nt < 4; ++nt)
                pa[nt] = *(const short8v*)&Pb[nt*16 + la][ks*32 + lb*8];
            #pragma unroll
            for (int ct = 0; ct < 8; ++ct) {
                #pragma unroll
                for (int nt = 0; nt < 4; ++nt)
                    acc[nt][ct] = mfma16(pa[nt], vreg[ks][ct], acc[nt][ct]);
            }
        }
    }

    // ---- epilogue: out = alpha*acc/l + x (sanitized; output always finite)
    const float alpha = alpha_p[0];
    float invl[4][4];
    #pragma unroll
    for (int nt = 0; nt < 4; ++nt)
        #pragma unroll
        for (int r = 0; r < 4; ++r)
            invl[nt][r] = alpha / fmaxf(row_l[nt*16 + lb*4 + r], 1.0e-20f);
    #pragma unroll
    for (int nt = 0; nt < 4; ++nt)
        #pragma unroll
        for (int ct = 0; ct < 8; ++ct) {
            const int c = w*128 + ct*16 + la;
            const size_t base = ((size_t)b*C_DIM + c)*N_DIM + n0 + nt*16 + lb*4;
            const float4 xa = *(const float4*)&x[base];
            float4 o;
            o.x = fmaf(fin(acc[nt][ct][0]), invl[nt][0], xa.x);
            o.y = fmaf(fin(acc[nt][ct][1]), invl[nt][1], xa.y);
            o.z = fmaf(fin(acc[nt][ct][2]), invl[nt][2], xa.z);
            o.w = fmaf(fin(acc[nt][ct][3]), invl[nt][3], xa.w);
            *(float4*)&out[base] = o;
        }
}

// ---------------------------------------------------------------------------
// Workspace (80 MiB proven): xth[0:32M) | xtl[32:64M) (vbf aliases) | qkt[64:80M)
// Pre-converted weights live in the HEAD OF d_out (1.5 MB; attn overwrites
// all of d_out afterwards; stream-ordered, redone every launch).
// Order: wprep, tx2 -> qkproj (reads xtl) -> vproj (overwrites xtl) -> attn.
// ---------------------------------------------------------------------------
extern "C" void kernel_launch(void* const* d_in, const int* in_sizes, int n_in,
                              void* d_out, int out_size, void* d_ws, size_t ws_size,
                              hipStream_t stream)
{
    const float* x     = (const float*)d_in[0];
    const float* Wq    = (const float*)d_in[1];
    const float* bq    = (const float*)d_in[2];
    const float* Wk    = (const float*)d_in[3];
    const float* bk    = (const float*)d_in[4];
    const float* Wv    = (const float*)d_in[5];
    const float* bv    = (const float*)d_in[6];
    const float* alpha = (const float*)d_in[7];
    float* out = (float*)d_out;

    unsigned short* xth = (unsigned short*)d_ws;
    unsigned short* xtl = (unsigned short*)((char*)d_ws + ((size_t)32 << 20));
    unsigned short* vbf = xtl;   // aliases xtl (dead after qkproj; stream-ordered)
    unsigned short* qkt = (unsigned short*)((char*)d_ws + ((size_t)64 << 20));

    unsigned short* Wqkh = (unsigned short*)d_out;          // 128x512
    unsigned short* Wqkl = Wqkh + (size_t)128 * C_DIM;      // 128x512
    unsigned short* Wvb  = Wqkl + (size_t)128 * C_DIM;      // 512x512

    wprep_kernel<<<dim3(640), 256, 0, stream>>>(Wq, Wk, Wv, Wqkh, Wqkl, Wvb);
    tx2_kernel  <<<dim3(16, 8, B_DIM), 256, 0, stream>>>(x, xth, xtl);
    qkproj_mfma <<<dim3(8, 1, B_DIM), 256, 0, stream>>>(xth, xtl, Wqkh, Wqkl, bq, bk, qkt);
    vproj_mfma  <<<dim3(8, 4, B_DIM), 256, 0, stream>>>(xth, Wvb, bv, vbf);
    attn_mfma   <<<dim3(512), 256, 0, stream>>>(qkt, vbf, x, alpha, out);
}

// Round 10
// 360.560 us; speedup vs baseline: 1.1190x; 1.1190x over previous
//
#include <hip/hip_runtime.h>
#include <math.h>

#define B_DIM  32
#define C_DIM  512
#define N_DIM  1024
#define LOG2E  1.44269504088896340736f
#define NEG_BIG (-1.0e30f)

typedef __attribute__((ext_vector_type(8))) __bf16 bf16x8;
typedef __attribute__((ext_vector_type(8))) short short8v;
typedef __attribute__((ext_vector_type(4))) short short4v;
typedef __attribute__((ext_vector_type(4))) float floatx4;

__device__ __forceinline__ unsigned short f2bf(float f) {      // RNE fp32->bf16
    unsigned u = __float_as_uint(f);
    return (unsigned short)((u + 0x7FFFu + ((u >> 16) & 1u)) >> 16);
}
__device__ __forceinline__ float bf2f(unsigned short h) {
    return __uint_as_float(((unsigned)h) << 16);
}
__device__ __forceinline__ floatx4 mfma16(short8v a, short8v b, floatx4 c) {
    return __builtin_amdgcn_mfma_f32_16x16x32_bf16(
        __builtin_bit_cast(bf16x8, a), __builtin_bit_cast(bf16x8, b), c, 0, 0, 0);
}
// non-finite -> 0 (diagnostic guard: output always finite, absmax stays readable)
__device__ __forceinline__ float fin(float v) {
    return (__builtin_fabsf(v) <= 1.0e30f) ? v : 0.0f;
}

// Raw barrier that does NOT drain vmcnt (unlike __syncthreads). Writer-side
// lgkmcnt(0) drains this wave's LDS writes; "memory" clobbers pin ordering.
#define BAR_LDS()  do {                                            \
    asm volatile("s_waitcnt lgkmcnt(0)" ::: "memory");             \
    __builtin_amdgcn_s_barrier();                                  \
    asm volatile("" ::: "memory");                                 \
} while (0)

// ---------------------------------------------------------------------------
// Weight prep (once per launch): Wq,Wk -> hi/lo bf16 [128][512]; Wv -> bf16.
// Written into the head of d_out (scratch until attn overwrites all of it).
// ---------------------------------------------------------------------------
__global__ __launch_bounds__(256) void wprep_kernel(
    const float* __restrict__ Wq, const float* __restrict__ Wk,
    const float* __restrict__ Wv,
    unsigned short* __restrict__ Wqkh, unsigned short* __restrict__ Wqkl,
    unsigned short* __restrict__ Wvb)
{
    const int r = blockIdx.x;            // 0..639
    const int t = threadIdx.x;
    if (t >= 128) return;
    if (r < 128) {
        const float* src = (r < 64) ? (Wq + (size_t)r * C_DIM)
                                    : (Wk + (size_t)(r - 64) * C_DIM);
        const float4 v = ((const float4*)src)[t];
        const float fv[4] = {v.x, v.y, v.z, v.w};
        short4v sh, sl;
        #pragma unroll
        for (int j = 0; j < 4; ++j) {
            const unsigned short h = f2bf(fv[j]);
            sh[j] = (short)h;
            sl[j] = (short)f2bf(fv[j] - bf2f(h));
        }
        *(short4v*)(Wqkh + (size_t)r * C_DIM + t*4) = sh;
        *(short4v*)(Wqkl + (size_t)r * C_DIM + t*4) = sl;
    } else {
        const int rv = r - 128;
        const float4 v = ((const float4*)(Wv + (size_t)rv * C_DIM))[t];
        short4v s;
        s[0] = (short)f2bf(v.x); s[1] = (short)f2bf(v.y);
        s[2] = (short)f2bf(v.z); s[3] = (short)f2bf(v.w);
        *(short4v*)(Wvb + (size_t)rv * C_DIM + t*4) = s;
    }
}

// ---------------------------------------------------------------------------
// Transpose+split x: [b][512][1024] fp32 -> xth/xtl bf16 [b][1024][512]
// ---------------------------------------------------------------------------
__global__ __launch_bounds__(256) void tx2_kernel(
    const float* __restrict__ x,
    unsigned short* __restrict__ xth, unsigned short* __restrict__ xtl)
{
    __shared__ float tile[64][65];
    const int n0 = blockIdx.x * 64, c0 = blockIdx.y * 64, b = blockIdx.z;
    const int t = threadIdx.x;

    #pragma unroll
    for (int p = 0; p < 4; ++p) {
        const int r = (t >> 4) + 16 * p;
        const float4 v = *(const float4*)(x + ((size_t)b*C_DIM + c0 + r)*N_DIM
                                          + n0 + (t & 15)*4);
        tile[r][(t&15)*4+0] = v.x;  tile[r][(t&15)*4+1] = v.y;
        tile[r][(t&15)*4+2] = v.z;  tile[r][(t&15)*4+3] = v.w;
    }
    __syncthreads();
    #pragma unroll
    for (int p = 0; p < 2; ++p) {
        const int rn = (t >> 3) + 32 * p;
        const int c8 = (t & 7) * 8;
        short8v hi, lo;
        #pragma unroll
        for (int j = 0; j < 8; ++j) {
            const float f = tile[c8 + j][rn];
            const unsigned short h = f2bf(f);
            hi[j] = (short)h;
            lo[j] = (short)f2bf(f - bf2f(h));
        }
        const size_t base = ((size_t)b*N_DIM + n0 + rn)*C_DIM + c0 + c8;
        *(short8v*)(xth + base) = hi;
        *(short8v*)(xtl + base) = lo;
    }
}

// ---------------------------------------------------------------------------
// Q,K projection, split-bf16 MFMA (proven); B-stage copies wprep weights.
// ---------------------------------------------------------------------------
__global__ __launch_bounds__(256) void qkproj_mfma(
    const unsigned short* __restrict__ xth, const unsigned short* __restrict__ xtl,
    const unsigned short* __restrict__ Wqkh, const unsigned short* __restrict__ Wqkl,
    const float* __restrict__ bq, const float* __restrict__ bk,
    unsigned short* __restrict__ qkt)
{
    __shared__ unsigned short Ah[128][40], Al[128][40];
    __shared__ unsigned short Bh[128][40], Bl[128][40];
    const int b = blockIdx.z, n0 = blockIdx.x * 128;
    const int t = threadIdx.x, w = t >> 6, l = t & 63;
    const int la = l & 15, lb = l >> 4;
    const int nh = (w & 1) * 64, oh = (w >> 1) * 64;

    floatx4 acc[4][4];
    #pragma unroll
    for (int i = 0; i < 4; ++i)
        #pragma unroll
        for (int j = 0; j < 4; ++j) acc[i][j] = (floatx4)0.0f;

    for (int k0 = 0; k0 < C_DIM; k0 += 32) {
        #pragma unroll
        for (int p = 0; p < 2; ++p) {       // A + B stages: 2x256x8 = 128x32 each
            const int idx = t + 256*p, row = idx >> 2, ch = idx & 3;
            const size_t g = ((size_t)b*N_DIM + n0 + row)*C_DIM + k0 + ch*8;
            *(short8v*)&Ah[row][ch*8] = *(const short8v*)(xth + g);
            *(short8v*)&Al[row][ch*8] = *(const short8v*)(xtl + g);
            const size_t gw = (size_t)row*C_DIM + k0 + ch*8;
            *(short8v*)&Bh[row][ch*8] = *(const short8v*)(Wqkh + gw);
            *(short8v*)&Bl[row][ch*8] = *(const short8v*)(Wqkl + gw);
        }
        __syncthreads();

        short8v ahf[4], alf[4], bhf[4], blf[4];
        #pragma unroll
        for (int nt = 0; nt < 4; ++nt) {
            ahf[nt] = *(const short8v*)&Ah[nh + nt*16 + la][lb*8];
            alf[nt] = *(const short8v*)&Al[nh + nt*16 + la][lb*8];
        }
        #pragma unroll
        for (int ot = 0; ot < 4; ++ot) {
            bhf[ot] = *(const short8v*)&Bh[oh + ot*16 + la][lb*8];
            blf[ot] = *(const short8v*)&Bl[oh + ot*16 + la][lb*8];
        }
        #pragma unroll
        for (int nt = 0; nt < 4; ++nt)
            #pragma unroll
            for (int ot = 0; ot < 4; ++ot) {
                acc[nt][ot] = mfma16(ahf[nt], bhf[ot], acc[nt][ot]);
                acc[nt][ot] = mfma16(ahf[nt], blf[ot], acc[nt][ot]);
                acc[nt][ot] = mfma16(alf[nt], bhf[ot], acc[nt][ot]);
            }
        __syncthreads();
    }

    const int plane = (oh == 0) ? 0 : 2;     // wave-uniform
    #pragma unroll
    for (int ot = 0; ot < 4; ++ot) {
        const int o = oh + ot*16 + la;
        const int c = o & 63;
        const float bias = (oh == 0) ? bq[o] : bk[o - 64];
        #pragma unroll
        for (int nt = 0; nt < 4; ++nt)
            #pragma unroll
            for (int r = 0; r < 4; ++r) {
                const int n = n0 + nh + nt*16 + lb*4 + r;
                const float f = acc[nt][ot][r] + bias;
                const unsigned short h = f2bf(f);
                const unsigned short lo16 = f2bf(f - bf2f(h));
                qkt[(((size_t)b*4 + plane    )*N_DIM + n)*64 + c] = h;
                qkt[(((size_t)b*4 + plane + 1)*N_DIM + n)*64 + c] = lo16;
            }
    }
}

// ---------------------------------------------------------------------------
// V projection, bf16 MFMA (proven): vbf [b][c][m] bf16, m innermost.
// ---------------------------------------------------------------------------
__global__ __launch_bounds__(256) void vproj_mfma(
    const unsigned short* __restrict__ xt,
    const unsigned short* __restrict__ Wvb, const float* __restrict__ bvv,
    unsigned short* __restrict__ vbf)
{
    __shared__ unsigned short Axs[128][40];
    __shared__ unsigned short Bws[128][40];
    const int b = blockIdx.z, m0 = blockIdx.x * 128, c0 = blockIdx.y * 128;
    const int t = threadIdx.x, w = t >> 6, l = t & 63;
    const int la = l & 15, lb = l >> 4;
    const int mh = (w & 1) * 64, chh = (w >> 1) * 64;

    floatx4 acc[4][4];
    #pragma unroll
    for (int i = 0; i < 4; ++i)
        #pragma unroll
        for (int j = 0; j < 4; ++j) acc[i][j] = (floatx4)0.0f;

    for (int k0 = 0; k0 < C_DIM; k0 += 32) {
        #pragma unroll
        for (int p = 0; p < 2; ++p) {        // A + B: 2x256x8 = 128x32 each
            const int idx = t + 256 * p;
            const int row = idx >> 2, ch = idx & 3;
            *(short8v*)&Axs[row][ch*8] =
                *(const short8v*)(xt + ((size_t)b*N_DIM + m0 + row)*C_DIM + k0 + ch*8);
            *(short8v*)&Bws[row][ch*8] =
                *(const short8v*)(Wvb + (size_t)(c0 + row)*C_DIM + k0 + ch*8);
        }
        __syncthreads();
        short8v af[4], bfv[4];
        #pragma unroll
        for (int mt = 0; mt < 4; ++mt)
            af[mt] = *(const short8v*)&Axs[mh + mt*16 + la][lb*8];
        #pragma unroll
        for (int ct = 0; ct < 4; ++ct)
            bfv[ct] = *(const short8v*)&Bws[chh + ct*16 + la][lb*8];
        #pragma unroll
        for (int mt = 0; mt < 4; ++mt)
            #pragma unroll
            for (int ct = 0; ct < 4; ++ct)
                acc[mt][ct] = mfma16(af[mt], bfv[ct], acc[mt][ct]);
        __syncthreads();
    }
    #pragma unroll
    for (int ct = 0; ct < 4; ++ct) {
        const int c = c0 + chh + ct*16 + la;
        const float bias = bvv[c];
        #pragma unroll
        for (int mt = 0; mt < 4; ++mt) {
            const int m = m0 + mh + mt*16 + lb*4;
            short4v s;
            #pragma unroll
            for (int r = 0; r < 4; ++r) s[r] = (short)f2bf(acc[mt][ct][r] + bias);
            *(short4v*)(vbf + ((size_t)b*C_DIM + c)*N_DIM + m) = s;
        }
    }
}

// ---------------------------------------------------------------------------
// Fused attention, QBLK=32 (R7's proven no-spill register budget: acc[2][8])
// with the R8-audited 2-barrier schedule and 40.3 KB LDS -> 4 blocks/CU
// (1024 blocks = exactly 4/CU, whole grid co-resident):
//  P0: prefetch V frags (this iter) + K tile (next iter) into registers
//  P1: energy MFMA -> S                         | B1
//  P1.5+P2: K regs -> LDS  ||  softmax S -> Pb  | B2
//  P3: rescale + PV (V from regs)               | (no barrier: audited)
// Hazards: Kwr(i)->Krd(i+1) by B2(i); Krd(i)->Kwr(i) by B1(i);
// Srd(i)->Swr(i+1) by B2(i); Pbrd(i)->Pbwr(i+1) by B1(i+1); row_* likewise.
// ---------------------------------------------------------------------------
__global__ __launch_bounds__(256, 2) void attn_mfma(
    const unsigned short* __restrict__ qkt,  // [b][4][1024][64]
    const unsigned short* __restrict__ vbf,  // [b][512][1024]
    const float* __restrict__ x,
    const float* __restrict__ alpha_p,
    float* __restrict__ out)
{
    __shared__ unsigned short Qh[32][72], Ql[32][72];
    __shared__ unsigned short Kh[64][68], Kl[64][68];   // pad 68: LDS 40,320B -> 4 blk/CU
    __shared__ __align__(16) float S[32][68];
    __shared__ unsigned short Pb[32][72];
    __shared__ float row_m[32], row_l[32], row_scale[32];

    const int id  = blockIdx.x;
    const int lin = (id & 7) * 128 + (id >> 3);   // XCD-contiguous (1024%8==0)
    const int b   = lin >> 5;
    const int n0  = (lin & 31) * 32;

    const int t = threadIdx.x, w = t >> 6, l = t & 63;
    const int la = l & 15, lb = l >> 4;
    const unsigned short* qkb = qkt + (size_t)b * 4 * N_DIM * 64;

    // ---- Q tile (both planes) -> LDS. Full coverage: 2 planes x 256 x 8.
    #pragma unroll
    for (int plane = 0; plane < 2; ++plane) {
        const int row = t >> 3;                // 0..31
        const int ch  = t & 7;                 // 0..7
        const short8v g = *(const short8v*)(qkb + ((size_t)plane*N_DIM + n0 + row)*64 + ch*8);
        if (plane == 0) *(short8v*)&Qh[row][ch*8] = g;
        else            *(short8v*)&Ql[row][ch*8] = g;
    }
    // ---- prologue K stage (tile 0). Full coverage: 2 planes x 512 x 8.
    #pragma unroll
    for (int pp = 0; pp < 4; ++pp) {
        const int plane = pp >> 1;
        const int idx   = t + 256 * (pp & 1);   // 0..511 per plane
        const int row   = idx >> 3;             // 0..63
        const int ch    = idx & 7;              // 0..7
        const short8v g = *(const short8v*)(qkb + ((size_t)(2 + plane)*N_DIM + row)*64 + ch*8);
        if (plane == 0) *(short8v*)&Kh[row][ch*8] = g;
        else            *(short8v*)&Kl[row][ch*8] = g;
    }
    if (t < 32) { row_m[t] = NEG_BIG; row_l[t] = 0.0f; row_scale[t] = 1.0f; }
    __syncthreads();   // prologue: full drain once

    floatx4 acc[2][8];   // [ntile][ctile]; n = nt*16+lb*4+r, c = w*128+ct*16+la
    #pragma unroll
    for (int i = 0; i < 2; ++i)
        #pragma unroll
        for (int j = 0; j < 8; ++j) acc[i][j] = (floatx4)0.0f;

    #pragma unroll 1
    for (int it = 0; it < 16; ++it) {
        const int m0  = it * 64;
        const int m0n = (it < 15) ? (m0 + 64) : 0;   // next tile (wrap unused)

        // ---- P0: issue prefetch loads (no waits here)
        short8v vreg[2][8];                     // V frags for THIS iter
        #pragma unroll
        for (int ks = 0; ks < 2; ++ks) {
            const unsigned short* vp =
                vbf + ((size_t)b*C_DIM + w*128 + la)*N_DIM + m0 + ks*32 + lb*8;
            #pragma unroll
            for (int ct = 0; ct < 8; ++ct)
                vreg[ks][ct] = *(const short8v*)(vp + (size_t)ct*16*N_DIM);
        }
        short8v kreg[4];                        // K tile for NEXT iter
        #pragma unroll
        for (int pp = 0; pp < 4; ++pp) {
            const int plane = pp >> 1;
            const int idx   = t + 256 * (pp & 1);
            const int row   = idx >> 3;
            const int ch    = idx & 7;
            kreg[pp] = *(const short8v*)(qkb + ((size_t)(2 + plane)*N_DIM + m0n + row)*64 + ch*8);
        }

        // ---- P1: energy MFMA (K tile m0 from LDS); split-bf16 3 terms
        {
            floatx4 e[2] = { (floatx4)0.0f, (floatx4)0.0f };
            #pragma unroll
            for (int ks = 0; ks < 2; ++ks) {
                const short8v ah = *(const short8v*)&Kh[w*16 + la][ks*32 + lb*8];
                const short8v al = *(const short8v*)&Kl[w*16 + la][ks*32 + lb*8];
                #pragma unroll
                for (int nt = 0; nt < 2; ++nt) {
                    const short8v bh = *(const short8v*)&Qh[nt*16 + la][ks*32 + lb*8];
                    const short8v bl = *(const short8v*)&Ql[nt*16 + la][ks*32 + lb*8];
                    e[nt] = mfma16(ah, bh, e[nt]);
                    e[nt] = mfma16(ah, bl, e[nt]);
                    e[nt] = mfma16(al, bh, e[nt]);
                }
            }
            #pragma unroll
            for (int nt = 0; nt < 2; ++nt) {   // D[m][n] -> S[n][m]
                floatx4 ev = e[nt];
                #pragma unroll
                for (int r = 0; r < 4; ++r) ev[r] = fin(ev[r]);
                *(floatx4*)&S[nt*16 + la][w*16 + lb*4] = ev;
            }
        }
        BAR_LDS();   // B1

        // ---- P1.5: write prefetched K tile -> LDS (for next iter)
        #pragma unroll
        for (int pp = 0; pp < 4; ++pp) {
            const int plane = pp >> 1;
            const int idx   = t + 256 * (pp & 1);
            const int row   = idx >> 3;
            const int ch    = idx & 7;
            if (plane == 0) *(short8v*)&Kh[row][ch*8] = kreg[pp];
            else            *(short8v*)&Kl[row][ch*8] = kreg[pp];
        }
        // ---- P2: online softmax (proven structure), emit P as bf16
        {
            const int row = t >> 3, seg = t & 7;
            const float4 sa = *(const float4*)&S[row][seg*8];
            const float4 sb = *(const float4*)&S[row][seg*8 + 4];
            float mx = fmaxf(fmaxf(fmaxf(sa.x,sa.y), fmaxf(sa.z,sa.w)),
                             fmaxf(fmaxf(sb.x,sb.y), fmaxf(sb.z,sb.w)));
            mx = fmaxf(mx, __shfl_xor(mx, 1));
            mx = fmaxf(mx, __shfl_xor(mx, 2));
            mx = fmaxf(mx, __shfl_xor(mx, 4));
            const float m_old = row_m[row];
            const float m_new = fmaxf(m_old, mx);
            const float p0 = exp2f((sa.x - m_new) * LOG2E);
            const float p1 = exp2f((sa.y - m_new) * LOG2E);
            const float p2 = exp2f((sa.z - m_new) * LOG2E);
            const float p3 = exp2f((sa.w - m_new) * LOG2E);
            const float p4 = exp2f((sb.x - m_new) * LOG2E);
            const float p5 = exp2f((sb.y - m_new) * LOG2E);
            const float p6 = exp2f((sb.z - m_new) * LOG2E);
            const float p7 = exp2f((sb.w - m_new) * LOG2E);
            float sum = ((p0+p1)+(p2+p3)) + ((p4+p5)+(p6+p7));
            sum += __shfl_xor(sum, 1);
            sum += __shfl_xor(sum, 2);
            sum += __shfl_xor(sum, 4);
            short8v pk;
            pk[0]=(short)f2bf(p0); pk[1]=(short)f2bf(p1);
            pk[2]=(short)f2bf(p2); pk[3]=(short)f2bf(p3);
            pk[4]=(short)f2bf(p4); pk[5]=(short)f2bf(p5);
            pk[6]=(short)f2bf(p6); pk[7]=(short)f2bf(p7);
            *(short8v*)&Pb[row][seg*8] = pk;
            if (seg == 0) {
                const float sc = exp2f((m_old - m_new) * LOG2E);
                row_scale[row] = sc;
                row_l[row] = row_l[row] * sc + sum;
                row_m[row] = m_new;
            }
        }
        BAR_LDS();   // B2

        // ---- P3: rescale + PV MFMA (V from prefetch regs); no barrier after
        {
            float fsc[2][4];
            #pragma unroll
            for (int nt = 0; nt < 2; ++nt)
                #pragma unroll
                for (int r = 0; r < 4; ++r) fsc[nt][r] = row_scale[nt*16 + lb*4 + r];
            #pragma unroll
            for (int nt = 0; nt < 2; ++nt)
                #pragma unroll
                for (int ct = 0; ct < 8; ++ct)
                    #pragma unroll
                    for (int r = 0; r < 4; ++r) acc[nt][ct][r] *= fsc[nt][r];
        }
        #pragma unroll
        for (int ks = 0; ks < 2; ++ks) {
            const short8v pa0 = *(const short8v*)&Pb[la][ks*32 + lb*8];
            const short8v pa1 = *(const short8v*)&Pb[16 + la][ks*32 + lb*8];
            #pragma unroll
            for (int ct = 0; ct < 8; ++ct) {
                acc[0][ct] = mfma16(pa0, vreg[ks][ct], acc[0][ct]);
                acc[1][ct] = mfma16(pa1, vreg[ks][ct], acc[1][ct]);
            }
        }
    }

    // ---- epilogue: out = alpha*acc/l + x (sanitized; output always finite)
    const float alpha = alpha_p[0];
    float invl[2][4];
    #pragma unroll
    for (int nt = 0; nt < 2; ++nt)
        #pragma unroll
        for (int r = 0; r < 4; ++r)
            invl[nt][r] = alpha / fmaxf(row_l[nt*16 + lb*4 + r], 1.0e-20f);
    #pragma unroll
    for (int nt = 0; nt < 2; ++nt)
        #pragma unroll
        for (int ct = 0; ct < 8; ++ct) {
            const int c = w*128 + ct*16 + la;
            const size_t base = ((size_t)b*C_DIM + c)*N_DIM + n0 + nt*16 + lb*4;
            const float4 xa = *(const float4*)&x[base];
            float4 o;
            o.x = fmaf(fin(acc[nt][ct][0]), invl[nt][0], xa.x);
            o.y = fmaf(fin(acc[nt][ct][1]), invl[nt][1], xa.y);
            o.z = fmaf(fin(acc[nt][ct][2]), invl[nt][2], xa.z);
            o.w = fmaf(fin(acc[nt][ct][3]), invl[nt][3], xa.w);
            *(float4*)&out[base] = o;
        }
}

// ---------------------------------------------------------------------------
// Workspace (80 MiB proven): xth[0:32M) | xtl[32:64M) (vbf aliases) | qkt[64:80M)
// Pre-converted weights live in the HEAD OF d_out (1.5 MB; attn overwrites
// all of d_out afterwards; stream-ordered, redone every launch).
// Order: wprep, tx2 -> qkproj (reads xtl) -> vproj (overwrites xtl) -> attn.
// ---------------------------------------------------------------------------
extern "C" void kernel_launch(void* const* d_in, const int* in_sizes, int n_in,
                              void* d_out, int out_size, void* d_ws, size_t ws_size,
                              hipStream_t stream)
{
    const float* x     = (const float*)d_in[0];
    const float* Wq    = (const float*)d_in[1];
    const float* bq    = (const float*)d_in[2];
    const float* Wk    = (const float*)d_in[3];
    const float* bk    = (const float*)d_in[4];
    const float* Wv    = (const float*)d_in[5];
    const float* bv    = (const float*)d_in[6];
    const float* alpha = (const float*)d_in[7];
    float* out = (float*)d_out;

    unsigned short* xth = (unsigned short*)d_ws;
    unsigned short* xtl = (unsigned short*)((char*)d_ws + ((size_t)32 << 20));
    unsigned short* vbf = xtl;   // aliases xtl (dead after qkproj; stream-ordered)
    unsigned short* qkt = (unsigned short*)((char*)d_ws + ((size_t)64 << 20));

    unsigned short* Wqkh = (unsigned short*)d_out;          // 128x512
    unsigned short* Wqkl = Wqkh + (size_t)128 * C_DIM;      // 128x512
    unsigned short* Wvb  = Wqkl + (size_t)128 * C_DIM;      // 512x512

    wprep_kernel<<<dim3(640), 256, 0, stream>>>(Wq, Wk, Wv, Wqkh, Wqkl, Wvb);
    tx2_kernel  <<<dim3(16, 8, B_DIM), 256, 0, stream>>>(x, xth, xtl);
    qkproj_mfma <<<dim3(8, 1, B_DIM), 256, 0, stream>>>(xth, xtl, Wqkh, Wqkl, bq, bk, qkt);
    vproj_mfma  <<<dim3(8, 4, B_DIM), 256, 0, stream>>>(xth, Wvb, bv, vbf);
    attn_mfma   <<<dim3(B_DIM * 32), 256, 0, stream>>>(qkt, vbf, x, alpha, out);
}